// Round 4
// baseline (463.177 us; speedup 1.0000x reference)
//
#include <hip/hip_runtime.h>

typedef unsigned short u16;
typedef __bf16 bf16x8 __attribute__((ext_vector_type(8)));
typedef float f32x4 __attribute__((ext_vector_type(4)));

#define D_MODEL 1024
#define NHEAD 16
#define DHEAD 64
#define BATCH 8
#define SEQ 1024
#define NROW 8192   // BATCH*SEQ

#define SBAR asm volatile("s_barrier" ::: "memory")

// ---------- helpers ----------
__device__ __forceinline__ u16 f2bf(float f) {
  union { float f; unsigned int u; } a; a.f = f;
  unsigned int u = a.u;
  return (u16)((u + 0x7fffu + ((u >> 16) & 1u)) >> 16);
}

// gelu_tanh(x) == x * sigmoid(2*c*(x+0.044715x^3)); single v_exp_f32, NaN-safe.
__device__ __forceinline__ float gelu_f(float x) {
  float y = 0.79788456080286535588f * (x + 0.044715f * x * x * x);
  return x / (1.0f + __expf(-2.0f * y));
}

__device__ __forceinline__ void async16(const void* gsrc, void* ldst) {
  __builtin_amdgcn_global_load_lds((__attribute__((address_space(1))) void*)gsrc,
                                   (__attribute__((address_space(3))) void*)ldst,
                                   16, 0, 0);
}

// ---------- weight fp32 [K,N] -> bf16 W^T [N,K] ----------
__global__ __launch_bounds__(256)
void wconv_kernel(const float* __restrict__ W, u16* __restrict__ WT, int K, int N) {
  __shared__ float tile[32][33];
  const int tx = threadIdx.x & 31, ty = threadIdx.x >> 5;
  const int n0 = blockIdx.x * 32, k0 = blockIdx.y * 32;
#pragma unroll
  for (int r = 0; r < 4; ++r)
    tile[ty + r * 8][tx] = W[(size_t)(k0 + ty + r * 8) * N + n0 + tx];
  __syncthreads();
#pragma unroll
  for (int r = 0; r < 4; ++r)
    WT[(size_t)(n0 + ty + r * 8) * K + k0 + tx] = f2bf(tile[tx][ty + r * 8]);
}

// ---------- layernorm fp32 -> bf16 ----------
__global__ __launch_bounds__(256)
void ln_kernel(const float* __restrict__ x, const float* __restrict__ gamma,
               const float* __restrict__ beta, u16* __restrict__ out) {
  const int row = blockIdx.x, t = threadIdx.x;
  const float4 v = ((const float4*)(x + (size_t)row * D_MODEL))[t];
  float s  = v.x + v.y + v.z + v.w;
  float s2 = v.x * v.x + v.y * v.y + v.z * v.z + v.w * v.w;
#pragma unroll
  for (int off = 32; off >= 1; off >>= 1) {
    s  += __shfl_down(s, off);
    s2 += __shfl_down(s2, off);
  }
  __shared__ float red[8];
  const int w = t >> 6, l = t & 63;
  if (l == 0) { red[w] = s; red[4 + w] = s2; }
  __syncthreads();
  s  = red[0] + red[1] + red[2] + red[3];
  s2 = red[4] + red[5] + red[6] + red[7];
  const float mean = s * (1.0f / D_MODEL);
  const float var  = s2 * (1.0f / D_MODEL) - mean * mean;
  const float inv  = rsqrtf(var + 1e-5f);
  const float4 ga = ((const float4*)gamma)[t];
  const float4 be = ((const float4*)beta)[t];
  ushort4 ov;
  ov.x = f2bf((v.x - mean) * inv * ga.x + be.x);
  ov.y = f2bf((v.y - mean) * inv * ga.y + be.y);
  ov.z = f2bf((v.z - mean) * inv * ga.z + be.z);
  ov.w = f2bf((v.w - mean) * inv * ga.w + be.w);
  ((ushort4*)out)[(size_t)row * 256 + t] = ov;
}

// ---------- 8-phase GEMM: C[M,N] = A[M,K](bf16) * B^T[N,K](bf16) ----------
// BM x 256 tile, BK=64, 8 waves (2M x 4N), wave tile (BM/2) x 64.
// LDS double-buffered; all next-tile global_load_lds issued in phase 0;
// one vmcnt(0) per K-tile at the last phase boundary; T2 chunk^row swizzle
// (pre-swizzled global source, linear LDS dest, swizzled ds_read).
#define MODE_QKV 0
#define MODE_F32_RES 2
#define MODE_GELU 3

template <int MODE, int MT>   // MT m-frags/wave: 8 -> BM=256, 4 -> BM=128
__global__ __launch_bounds__(512, 2)
void gemm8(const u16* __restrict__ A, const u16* __restrict__ BT,
           const float* __restrict__ bias, const float* __restrict__ resid,
           void* __restrict__ outp, u16* __restrict__ out2, u16* __restrict__ out3,
           int mtiles, int ntiles, int N, int K) {
  constexpr int BM = MT * 32;
  constexpr int P  = MT / 2;            // phases per K-tile
  constexpr int LA = BM / 64;           // A gload_lds per thread per tile
  constexpr int LB = 4;                 // B gload_lds per thread per tile
  __shared__ u16 sA[2][BM * 64];
  __shared__ u16 sB[2][256 * 64];

  const int t = threadIdx.x, w = t >> 6, l = t & 63;
  const int c = l & 15, g = l >> 4;
  const int wr = w >> 2, wc = w & 3;

  // XCD-aware bijective swizzle (all launches have nwg % 8 == 0)
  const int nwg = mtiles * ntiles;
  const int orig = blockIdx.x;
  const int wgid = (orig & 7) * (nwg >> 3) + (orig >> 3);
  const int bm = wgid / ntiles, bn = wgid % ntiles;

  const int ldb = K * 2;                // bytes per row (<= 8192)
  const char* Ab = (const char*)A + (size_t)bm * BM * ldb;
  const char* Bb = (const char*)BT + (size_t)bn * 256 * ldb;

  // staging source offsets: load i covers linear LDS off16 = i*512 + t
  int aoff[LA], boff[LB];
#pragma unroll
  for (int i = 0; i < LA; ++i) {
    const int o = i * 512 + t, row = o >> 3, chg = (o & 7) ^ (row & 7);
    aoff[i] = row * ldb + chg * 16;
  }
#pragma unroll
  for (int i = 0; i < LB; ++i) {
    const int o = i * 512 + t, row = o >> 3, chg = (o & 7) ^ (row & 7);
    boff[i] = row * ldb + chg * 16;
  }

  auto stage = [&](int b, int k0) {
    const int kb = k0 * 2;
#pragma unroll
    for (int i = 0; i < LA; ++i)
      async16(Ab + (size_t)(aoff[i] + kb), (char*)sA[b] + (i * 512 + w * 64) * 16);
#pragma unroll
    for (int i = 0; i < LB; ++i)
      async16(Bb + (size_t)(boff[i] + kb), (char*)sB[b] + (i * 512 + w * 64) * 16);
  };

  auto ldA = [&](int cur, int mf, int ks) -> bf16x8 {
    const int row = wr * (MT * 16) + mf * 16 + c;
    return *(const bf16x8*)((const char*)sA[cur] + row * 128 + (((ks << 2) + g) ^ (row & 7)) * 16);
  };
  auto ldB = [&](int cur, int nf, int ks) -> bf16x8 {
    const int row = wc * 64 + nf * 16 + c;
    return *(const bf16x8*)((const char*)sB[cur] + row * 128 + (((ks << 2) + g) ^ (row & 7)) * 16);
  };

  f32x4 acc[MT][4] = {};

  stage(0, 0);
  asm volatile("s_waitcnt vmcnt(0)" ::: "memory");
  SBAR;

  const int nt = K >> 6;
  for (int it = 0; it < nt; ++it) {
    const int cur = it & 1;
    bf16x8 bfr[4][2];
#pragma unroll
    for (int p = 0; p < P; ++p) {
      if (p == 0 && it + 1 < nt) stage(cur ^ 1, (it + 1) << 6);  // prefetch, in flight all tile
      bf16x8 af[2][2];
#pragma unroll
      for (int mi = 0; mi < 2; ++mi)
#pragma unroll
        for (int ks = 0; ks < 2; ++ks)
          af[mi][ks] = ldA(cur, p * 2 + mi, ks);
      if (p == 0) {
#pragma unroll
        for (int n = 0; n < 4; ++n)
#pragma unroll
          for (int ks = 0; ks < 2; ++ks)
            bfr[n][ks] = ldB(cur, n, ks);
      }
      SBAR;                                   // waves aligned: loads issued vs MFMA
      __builtin_amdgcn_s_setprio(1);
#pragma unroll
      for (int ks = 0; ks < 2; ++ks)
#pragma unroll
        for (int mi = 0; mi < 2; ++mi)
#pragma unroll
          for (int n = 0; n < 4; ++n)
            acc[p * 2 + mi][n] = __builtin_amdgcn_mfma_f32_16x16x32_bf16(
                af[mi][ks], bfr[n][ks], acc[p * 2 + mi][n], 0, 0, 0);
      __builtin_amdgcn_s_setprio(0);
      if (p + 1 < P) {
        SBAR;
      } else {
        asm volatile("s_waitcnt vmcnt(0)" ::: "memory");  // next buffer resident
        SBAR;                                             // all waves done reading cur
      }
    }
  }

#pragma unroll
  for (int m = 0; m < MT; ++m) {
    const int r0 = bm * BM + wr * (MT * 16) + m * 16 + g * 4;
#pragma unroll
    for (int n = 0; n < 4; ++n) {
      const int cc = bn * 256 + wc * 64 + n * 16 + c;
#pragma unroll
      for (int i = 0; i < 4; ++i) {
        const int r = r0 + i;
        const float v = acc[m][n][i];
        if constexpr (MODE == MODE_QKV) {
          const int sel = cc >> 10, ccl = cc & 1023;
          const int bb = r >> 10, tt = r & 1023, h = ccl >> 6, dh = ccl & 63;
          if (sel == 0)
            ((u16*)outp)[(((size_t)bb * NHEAD + h) * SEQ + tt) * DHEAD + dh] = f2bf(v);
          else if (sel == 1)
            out2[(((size_t)bb * NHEAD + h) * SEQ + tt) * DHEAD + dh] = f2bf(v);
          else
            out3[(((size_t)bb * NHEAD + h) * DHEAD + dh) * SEQ + tt] = f2bf(v);
        } else if constexpr (MODE == MODE_F32_RES) {
          const size_t idx = (size_t)r * N + cc;
          ((float*)outp)[idx] = v + bias[cc] + resid[idx];
        } else {
          const size_t idx = (size_t)r * N + cc;
          ((u16*)outp)[idx] = f2bf(gelu_f(v + bias[cc]));
        }
      }
    }
  }
}

// ---------- causal flash attention ----------
// 4 waves/block, QBLK=32 rows/wave, KVBLK=64, K/V LDS double-buffered
// via global_load_lds with XOR chunk swizzle; counted vmcnt + raw barriers.
__global__ __launch_bounds__(256, 3)
void attn_kernel(const u16* __restrict__ q, const u16* __restrict__ k,
                 const u16* __restrict__ vT, u16* __restrict__ z) {
  __shared__ u16 sK[2][64 * 64];
  __shared__ u16 sV[2][64 * 64];
  __shared__ u16 pb[4][32 * 64];

  const int t = threadIdx.x, w = t >> 6, l = t & 63;
  const int c = l & 15, g = l >> 4;
  const int bh = blockIdx.y;
  const int qb0 = blockIdx.x * 128;
  const int qw0 = qb0 + w * 32;

  const u16* qbase = q  + (size_t)bh * SEQ * DHEAD;
  const u16* kbase = k  + (size_t)bh * SEQ * DHEAD;
  const u16* vbase = vT + (size_t)bh * DHEAD * SEQ;

  bf16x8 qf[2][2];
#pragma unroll
  for (int j = 0; j < 2; ++j)
#pragma unroll
    for (int hh = 0; hh < 2; ++hh)
      qf[j][hh] = *(const bf16x8*)&qbase[(size_t)(qw0 + j * 16 + c) * DHEAD + hh * 32 + g * 8];

  f32x4 o[4][2] = {};
  float m[2]  = {-3.0e38f, -3.0e38f};
  float ls[2] = {0.0f, 0.0f};

  const int r8 = l >> 3, ch = l & 7;
  const int sw16 = (ch ^ r8) * 16;

  auto stage = [&](int buf, int kt) {
    const int kb0 = kt * 64;
#pragma unroll
    for (int i = 0; i < 2; ++i) {
      const int row = w * 8 + i * 32 + r8;
      async16((const char*)kbase + (size_t)(kb0 + row) * 128 + sw16,
              (char*)sK[buf] + w * 1024 + i * 4096);
      async16((const char*)vbase + (size_t)row * (SEQ * 2) + (size_t)kb0 * 2 + sw16,
              (char*)sV[buf] + w * 1024 + i * 4096);
    }
  };

  const int nkt = blockIdx.x * 2 + 2;
  stage(0, 0);

  for (int kt = 0; kt < nkt; ++kt) {
    const int cur = kt & 1;
    if (kt + 1 < nkt) {
      stage(cur ^ 1, kt + 1);
      asm volatile("s_waitcnt vmcnt(4)" ::: "memory");
    } else {
      asm volatile("s_waitcnt vmcnt(0)" ::: "memory");
    }
    __builtin_amdgcn_s_barrier();

    const int kb0 = kt * 64;
    if (kb0 < qw0 + 32) {
      const u16* sKc = sK[cur];
      const u16* sVc = sV[cur];
      const int cx = c & 7;

      f32x4 st[4][2];
#pragma unroll
      for (int s = 0; s < 4; ++s) {
        const int row = s * 16 + c;
        bf16x8 kf0 = *(const bf16x8*)&sKc[row * 64 + ((0 + g) ^ cx) * 8];
        bf16x8 kf1 = *(const bf16x8*)&sKc[row * 64 + ((4 + g) ^ cx) * 8];
#pragma unroll
        for (int j = 0; j < 2; ++j) {
          f32x4 z4 = {};
          z4 = __builtin_amdgcn_mfma_f32_16x16x32_bf16(kf0, qf[j][0], z4, 0, 0, 0);
          z4 = __builtin_amdgcn_mfma_f32_16x16x32_bf16(kf1, qf[j][1], z4, 0, 0, 0);
          st[s][j] = z4;
        }
      }

      const bool full = (kb0 + 64 <= qw0 + 1);
      float tmax[2] = {-3.0e38f, -3.0e38f};
#pragma unroll
      for (int s = 0; s < 4; ++s)
#pragma unroll
        for (int j = 0; j < 2; ++j)
#pragma unroll
          for (int i = 0; i < 4; ++i) {
            float vsc = st[s][j][i] * 0.125f;
            if (!full) {
              const int key = kb0 + s * 16 + g * 4 + i;
              vsc = (key <= qw0 + j * 16 + c) ? vsc : -1.0e30f;
            }
            st[s][j][i] = vsc;
            tmax[j] = fmaxf(tmax[j], vsc);
          }
#pragma unroll
      for (int j = 0; j < 2; ++j) {
        tmax[j] = fmaxf(tmax[j], __shfl_xor(tmax[j], 16));
        tmax[j] = fmaxf(tmax[j], __shfl_xor(tmax[j], 32));
      }
      float mnew[2], sc[2], psum[2];
#pragma unroll
      for (int j = 0; j < 2; ++j) {
        mnew[j] = fmaxf(m[j], tmax[j]);
        sc[j]   = __expf(m[j] - mnew[j]);
        psum[j] = 0.0f;
      }
#pragma unroll
      for (int s = 0; s < 4; ++s)
#pragma unroll
        for (int j = 0; j < 2; ++j)
#pragma unroll
          for (int i = 0; i < 4; ++i) {
            const float pv = __expf(st[s][j][i] - mnew[j]);
            st[s][j][i] = pv;
            psum[j] += pv;
          }
#pragma unroll
      for (int j = 0; j < 2; ++j) {
        psum[j] += __shfl_xor(psum[j], 16);
        psum[j] += __shfl_xor(psum[j], 32);
        ls[j] = ls[j] * sc[j] + psum[j];
        m[j]  = mnew[j];
#pragma unroll
        for (int d = 0; d < 4; ++d) o[d][j] = o[d][j] * sc[j];
      }

      u16* pw = pb[w];
#pragma unroll
      for (int s = 0; s < 4; ++s)
#pragma unroll
        for (int j = 0; j < 2; ++j) {
          const int row = j * 16 + c;
          const int swz = (s * 2 + (g >> 1)) ^ cx;
          ushort4 pv4;
          pv4.x = f2bf(st[s][j][0]); pv4.y = f2bf(st[s][j][1]);
          pv4.z = f2bf(st[s][j][2]); pv4.w = f2bf(st[s][j][3]);
          *(ushort4*)&pw[row * 64 + swz * 8 + (g & 1) * 4] = pv4;
        }

      bf16x8 pf[2][2];
#pragma unroll
      for (int j = 0; j < 2; ++j)
#pragma unroll
        for (int ks = 0; ks < 2; ++ks)
          pf[j][ks] = *(const bf16x8*)&pw[(j * 16 + c) * 64 + ((ks * 4 + g) ^ cx) * 8];

#pragma unroll
      for (int d = 0; d < 4; ++d) {
        const int vrow = d * 16 + c;
#pragma unroll
        for (int ks = 0; ks < 2; ++ks) {
          bf16x8 vf = *(const bf16x8*)&sVc[vrow * 64 + ((ks * 4 + g) ^ cx) * 8];
#pragma unroll
          for (int j = 0; j < 2; ++j)
            o[d][j] = __builtin_amdgcn_mfma_f32_16x16x32_bf16(vf, pf[j][ks], o[d][j], 0, 0, 0);
        }
      }
    }
    __builtin_amdgcn_s_barrier();
  }

  const int b = bh >> 4, h = bh & 15;
#pragma unroll
  for (int j = 0; j < 2; ++j) {
    const float inv = 1.0f / ls[j];
    const int qrow = qw0 + j * 16 + c;
    u16* zr = z + ((size_t)b * SEQ + qrow) * D_MODEL + h * DHEAD;
#pragma unroll
    for (int d = 0; d < 4; ++d) {
      ushort4 ov;
      ov.x = f2bf(o[d][j][0] * inv); ov.y = f2bf(o[d][j][1] * inv);
      ov.z = f2bf(o[d][j][2] * inv); ov.w = f2bf(o[d][j][3] * inv);
      *(ushort4*)&zr[d * 16 + g * 4] = ov;
    }
  }
}

// ---------- host ----------
extern "C" void kernel_launch(void* const* d_in, const int* in_sizes, int n_in,
                              void* d_out, int out_size, void* d_ws, size_t ws_size,
                              hipStream_t stream) {
  (void)in_sizes; (void)n_in; (void)out_size; (void)ws_size;
  const float* x   = (const float*)d_in[0];
  const float* g1  = (const float*)d_in[1];
  const float* s1  = (const float*)d_in[2];
  const float* Wq  = (const float*)d_in[3];
  const float* Wk  = (const float*)d_in[4];
  const float* Wv  = (const float*)d_in[5];
  const float* Wo  = (const float*)d_in[6];
  const float* bo  = (const float*)d_in[7];
  const float* g2  = (const float*)d_in[8];
  const float* s2  = (const float*)d_in[9];
  const float* W1  = (const float*)d_in[10];
  const float* b1  = (const float*)d_in[11];
  const float* W2  = (const float*)d_in[12];
  const float* b2  = (const float*)d_in[13];
  float* out = (float*)d_out;
  char* ws = (char*)d_ws;
  const size_t MB = 1024 * 1024;

  u16* wqkvT = (u16*)(ws + 0 * MB);   // 6 MB  [3072,1024] = Wq^T | Wk^T | Wv^T
  u16* woT = (u16*)(ws + 6 * MB);     // 2 MB
  u16* w1T = (u16*)(ws + 8 * MB);     // 8 MB  [4096,1024]
  u16* w2T = (u16*)(ws + 16 * MB);    // 8 MB  [1024,4096]
  u16* x1  = (u16*)(ws + 24 * MB);    // 16 MB
  u16* qb  = (u16*)(ws + 40 * MB);    // 16 MB
  u16* kb  = (u16*)(ws + 56 * MB);    // 16 MB
  u16* vb  = (u16*)(ws + 72 * MB);    // 16 MB
  u16* hb  = (u16*)(ws + 24 * MB);    // 64 MB, aliases x1/q/k/v (dead by MLP1)
  u16* zb  = (u16*)(ws + 88 * MB);    // 16 MB
  u16* y1  = (u16*)(ws + 88 * MB);    // 16 MB, aliases zb (dead after Wo proj)
  float* yb = (float*)(ws + 104 * MB); // 32 MB -> total 136 MB

  // 1. weight convert + transpose
  wconv_kernel<<<dim3(32, 32), 256, 0, stream>>>(Wq, wqkvT, 1024, 1024);
  wconv_kernel<<<dim3(32, 32), 256, 0, stream>>>(Wk, wqkvT + 1024 * 1024, 1024, 1024);
  wconv_kernel<<<dim3(32, 32), 256, 0, stream>>>(Wv, wqkvT + 2048 * 1024, 1024, 1024);
  wconv_kernel<<<dim3(32, 32), 256, 0, stream>>>(Wo, woT, 1024, 1024);
  wconv_kernel<<<dim3(128, 32), 256, 0, stream>>>(W1, w1T, 1024, 4096);
  wconv_kernel<<<dim3(32, 128), 256, 0, stream>>>(W2, w2T, 4096, 1024);
  // 2. LN1
  ln_kernel<<<NROW, 256, 0, stream>>>(x, g1, s1, x1);
  // 3. fused QKV projection (N=3072), head-split scatter epilogue
  gemm8<MODE_QKV, 4><<<64 * 12, 512, 0, stream>>>(x1, wqkvT, nullptr, nullptr,
                                                  qb, kb, vb, 64, 12, 3072, 1024);
  // 4. attention
  attn_kernel<<<dim3(8, 128), 256, 0, stream>>>(qb, kb, vb, zb);
  // 5. output projection + residual (fp32 y)
  gemm8<MODE_F32_RES, 4><<<64 * 4, 512, 0, stream>>>(zb, woT, bo, x,
                                                     yb, nullptr, nullptr, 64, 4, 1024, 1024);
  // 6. LN2
  ln_kernel<<<NROW, 256, 0, stream>>>(yb, g2, s2, y1);
  // 7. MLP up + GELU (256^2 tiles)
  gemm8<MODE_GELU, 8><<<32 * 16, 512, 0, stream>>>(y1, w1T, b1, nullptr,
                                                   hb, nullptr, nullptr, 32, 16, 4096, 1024);
  // 8. MLP down + bias + residual -> out
  gemm8<MODE_F32_RES, 4><<<64 * 4, 512, 0, stream>>>(hb, w2T, b2, yb,
                                                     out, nullptr, nullptr, 64, 4, 1024, 4096);
}

// Round 6
// 454.880 us; speedup vs baseline: 1.0182x; 1.0182x over previous
//
#include <hip/hip_runtime.h>

typedef unsigned short u16;
typedef __bf16 bf16x8 __attribute__((ext_vector_type(8)));
typedef float f32x4 __attribute__((ext_vector_type(4)));

#define D_MODEL 1024
#define NHEAD 16
#define DHEAD 64
#define BATCH 8
#define SEQ 1024
#define NROW 8192   // BATCH*SEQ

#define SBAR asm volatile("s_barrier" ::: "memory")

// ---------- helpers ----------
__device__ __forceinline__ u16 f2bf(float f) {
  union { float f; unsigned int u; } a; a.f = f;
  unsigned int u = a.u;
  return (u16)((u + 0x7fffu + ((u >> 16) & 1u)) >> 16);
}

// gelu_tanh(x) == x * sigmoid(2*c*(x+0.044715x^3)); single v_exp_f32, NaN-safe.
__device__ __forceinline__ float gelu_f(float x) {
  float y = 0.79788456080286535588f * (x + 0.044715f * x * x * x);
  return x / (1.0f + __expf(-2.0f * y));
}

__device__ __forceinline__ void async16(const void* gsrc, void* ldst) {
  __builtin_amdgcn_global_load_lds((__attribute__((address_space(1))) void*)gsrc,
                                   (__attribute__((address_space(3))) void*)ldst,
                                   16, 0, 0);
}

template <int N> __device__ __forceinline__ void vmwait() {
  if constexpr (N >= 8)      asm volatile("s_waitcnt vmcnt(8)" ::: "memory");
  else if constexpr (N == 6) asm volatile("s_waitcnt vmcnt(6)" ::: "memory");
  else                       asm volatile("s_waitcnt vmcnt(0)" ::: "memory");
}

// ---------- weight fp32 [K,N] -> bf16 W^T [N,K] ----------
__global__ __launch_bounds__(256)
void wconv_kernel(const float* __restrict__ W, u16* __restrict__ WT, int K, int N) {
  __shared__ float tile[32][33];
  const int tx = threadIdx.x & 31, ty = threadIdx.x >> 5;
  const int n0 = blockIdx.x * 32, k0 = blockIdx.y * 32;
#pragma unroll
  for (int r = 0; r < 4; ++r)
    tile[ty + r * 8][tx] = W[(size_t)(k0 + ty + r * 8) * N + n0 + tx];
  __syncthreads();
#pragma unroll
  for (int r = 0; r < 4; ++r)
    WT[(size_t)(n0 + ty + r * 8) * K + k0 + tx] = f2bf(tile[tx][ty + r * 8]);
}

// ---------- layernorm fp32 -> bf16 ----------
__global__ __launch_bounds__(256)
void ln_kernel(const float* __restrict__ x, const float* __restrict__ gamma,
               const float* __restrict__ beta, u16* __restrict__ out) {
  const int row = blockIdx.x, t = threadIdx.x;
  const float4 v = ((const float4*)(x + (size_t)row * D_MODEL))[t];
  float s  = v.x + v.y + v.z + v.w;
  float s2 = v.x * v.x + v.y * v.y + v.z * v.z + v.w * v.w;
#pragma unroll
  for (int off = 32; off >= 1; off >>= 1) {
    s  += __shfl_down(s, off);
    s2 += __shfl_down(s2, off);
  }
  __shared__ float red[8];
  const int w = t >> 6, l = t & 63;
  if (l == 0) { red[w] = s; red[4 + w] = s2; }
  __syncthreads();
  s  = red[0] + red[1] + red[2] + red[3];
  s2 = red[4] + red[5] + red[6] + red[7];
  const float mean = s * (1.0f / D_MODEL);
  const float var  = s2 * (1.0f / D_MODEL) - mean * mean;
  const float inv  = rsqrtf(var + 1e-5f);
  const float4 ga = ((const float4*)gamma)[t];
  const float4 be = ((const float4*)beta)[t];
  ushort4 ov;
  ov.x = f2bf((v.x - mean) * inv * ga.x + be.x);
  ov.y = f2bf((v.y - mean) * inv * ga.y + be.y);
  ov.z = f2bf((v.z - mean) * inv * ga.z + be.z);
  ov.w = f2bf((v.w - mean) * inv * ga.w + be.w);
  ((ushort4*)out)[(size_t)row * 256 + t] = ov;
}

// ---------- 8-phase GEMM with counted-vmcnt pipeline ----------
// C[M,N] = A[M,K](bf16) * B^T[N,K](bf16). BM x 256 tile, BK=64, 8 waves.
// Loads for tile it+2 issued at END of tile it (after reads-done barrier frees
// buf[cur]); vmcnt(LA+LB) waits only for tile it+1's loads -> it+2's stay in
// flight across barriers (T4). stage() second arg is a K ELEMENT offset.
// T2 chunk^row swizzle: pre-swizzled global src, linear LDS dest, swizzled ds_read.
#define MODE_QKV 0
#define MODE_F32_RES 2
#define MODE_GELU 3

template <int MODE, int MT>   // MT m-frags/wave: 8 -> BM=256, 4 -> BM=128
__global__ __launch_bounds__(512, 2)
void gemm8(const u16* __restrict__ A, const u16* __restrict__ BT,
           const float* __restrict__ bias, const float* __restrict__ resid,
           void* __restrict__ outp, u16* __restrict__ out2, u16* __restrict__ out3,
           int mtiles, int ntiles, int N, int K) {
  constexpr int BM = MT * 32;
  constexpr int P  = MT / 2;            // phases per K-tile
  constexpr int LA = BM / 64;           // A gload_lds per thread per tile
  constexpr int LB = 4;                 // B gload_lds per thread per tile
  __shared__ u16 sA[2][BM * 64];
  __shared__ u16 sB[2][256 * 64];

  const int t = threadIdx.x, w = t >> 6, l = t & 63;
  const int c = l & 15, g = l >> 4;
  const int wr = w >> 2, wc = w & 3;

  // XCD-aware bijective swizzle (all launches have nwg % 8 == 0)
  const int nwg = mtiles * ntiles;
  const int orig = blockIdx.x;
  const int wgid = (orig & 7) * (nwg >> 3) + (orig >> 3);
  const int bm = wgid / ntiles, bn = wgid % ntiles;

  const int ldb = K * 2;                // bytes per row
  const char* Ab = (const char*)A + (size_t)bm * BM * ldb;
  const char* Bb = (const char*)BT + (size_t)bn * 256 * ldb;

  // staging source offsets: load i covers linear LDS off16 = i*512 + t
  int aoff[LA], boff[LB];
#pragma unroll
  for (int i = 0; i < LA; ++i) {
    const int o = i * 512 + t, row = o >> 3, chg = (o & 7) ^ (row & 7);
    aoff[i] = row * ldb + chg * 16;
  }
#pragma unroll
  for (int i = 0; i < LB; ++i) {
    const int o = i * 512 + t, row = o >> 3, chg = (o & 7) ^ (row & 7);
    boff[i] = row * ldb + chg * 16;
  }

  auto stage = [&](int b, int k0) {     // k0: K element offset of the tile
    const int kb = k0 * 2;
#pragma unroll
    for (int i = 0; i < LA; ++i)
      async16(Ab + (size_t)(aoff[i] + kb), (char*)sA[b] + (i * 512 + w * 64) * 16);
#pragma unroll
    for (int i = 0; i < LB; ++i)
      async16(Bb + (size_t)(boff[i] + kb), (char*)sB[b] + (i * 512 + w * 64) * 16);
  };

  auto ldA = [&](int cur, int mf, int ks) -> bf16x8 {
    const int row = wr * (MT * 16) + mf * 16 + c;
    return *(const bf16x8*)((const char*)sA[cur] + row * 128 + (((ks << 2) + g) ^ (row & 7)) * 16);
  };
  auto ldB = [&](int cur, int nf, int ks) -> bf16x8 {
    const int row = wc * 64 + nf * 16 + c;
    return *(const bf16x8*)((const char*)sB[cur] + row * 128 + (((ks << 2) + g) ^ (row & 7)) * 16);
  };

  f32x4 acc[MT][4] = {};

  const int nt = K >> 6;                // always >= 16 here
  stage(0, 0);
  stage(1, 64);
  vmwait<LA + LB>();                    // tile 0 resident; tile 1 in flight
  SBAR;

  for (int it = 0; it < nt; ++it) {
    const int cur = it & 1;
    bf16x8 bfr[4][2];
#pragma unroll
    for (int p = 0; p < P; ++p) {
      bf16x8 af[2][2];
#pragma unroll
      for (int mi = 0; mi < 2; ++mi)
#pragma unroll
        for (int ks = 0; ks < 2; ++ks)
          af[mi][ks] = ldA(cur, p * 2 + mi, ks);
      if (p == 0) {
#pragma unroll
        for (int n = 0; n < 4; ++n)
#pragma unroll
          for (int ks = 0; ks < 2; ++ks)
            bfr[n][ks] = ldB(cur, n, ks);
      }
      SBAR;                                   // align waves: reads issued vs MFMA
      __builtin_amdgcn_s_setprio(1);
#pragma unroll
      for (int ks = 0; ks < 2; ++ks)
#pragma unroll
        for (int mi = 0; mi < 2; ++mi)
#pragma unroll
          for (int n = 0; n < 4; ++n)
            acc[p * 2 + mi][n] = __builtin_amdgcn_mfma_f32_16x16x32_bf16(
                af[mi][ks], bfr[n][ks], acc[p * 2 + mi][n], 0, 0, 0);
      __builtin_amdgcn_s_setprio(0);
      if (p + 1 < P) {
        SBAR;                                 // phase done
      } else {
        // reads-done barrier: drain DS queue first so no wave's outstanding
        // ds_read of buf[cur] can race the refill DMA below.
        asm volatile("s_waitcnt lgkmcnt(0)" ::: "memory");
        SBAR;
      }
    }
    // buf[cur] free (all waves past barrier); refill it 2 tiles ahead.
    if (it + 2 < nt) {
      stage(cur, (it + 2) << 6);              // newest LA+LB loads in flight
      vmwait<LA + LB>();                      // wait ONLY for tile it+1's loads
      SBAR;
    } else if (it + 1 < nt) {
      vmwait<0>();                            // epilogue drain: tile it+1 resident
      SBAR;
    }
  }

#pragma unroll
  for (int m = 0; m < MT; ++m) {
    const int r0 = bm * BM + wr * (MT * 16) + m * 16 + g * 4;
#pragma unroll
    for (int n = 0; n < 4; ++n) {
      const int cc = bn * 256 + wc * 64 + n * 16 + c;
#pragma unroll
      for (int i = 0; i < 4; ++i) {
        const int r = r0 + i;
        const float v = acc[m][n][i];
        if constexpr (MODE == MODE_QKV) {
          const int sel = cc >> 10, ccl = cc & 1023;
          const int bb = r >> 10, tt = r & 1023, h = ccl >> 6, dh = ccl & 63;
          if (sel == 0)
            ((u16*)outp)[(((size_t)bb * NHEAD + h) * SEQ + tt) * DHEAD + dh] = f2bf(v);
          else if (sel == 1)
            out2[(((size_t)bb * NHEAD + h) * SEQ + tt) * DHEAD + dh] = f2bf(v);
          else
            out3[(((size_t)bb * NHEAD + h) * DHEAD + dh) * SEQ + tt] = f2bf(v);
        } else if constexpr (MODE == MODE_F32_RES) {
          const size_t idx = (size_t)r * N + cc;
          ((float*)outp)[idx] = v + bias[cc] + resid[idx];
        } else {
          const size_t idx = (size_t)r * N + cc;
          ((u16*)outp)[idx] = f2bf(gelu_f(v + bias[cc]));
        }
      }
    }
  }
}

// ---------- causal flash attention ----------
// 4 waves/block, QBLK=32 rows/wave, KVBLK=64, K/V LDS double-buffered
// via global_load_lds with XOR chunk swizzle; counted vmcnt + raw barriers.
__global__ __launch_bounds__(256, 3)
void attn_kernel(const u16* __restrict__ q, const u16* __restrict__ k,
                 const u16* __restrict__ vT, u16* __restrict__ z) {
  __shared__ u16 sK[2][64 * 64];
  __shared__ u16 sV[2][64 * 64];
  __shared__ u16 pb[4][32 * 64];

  const int t = threadIdx.x, w = t >> 6, l = t & 63;
  const int c = l & 15, g = l >> 4;
  const int bh = blockIdx.y;
  const int qb0 = blockIdx.x * 128;
  const int qw0 = qb0 + w * 32;

  const u16* qbase = q  + (size_t)bh * SEQ * DHEAD;
  const u16* kbase = k  + (size_t)bh * SEQ * DHEAD;
  const u16* vbase = vT + (size_t)bh * DHEAD * SEQ;

  bf16x8 qf[2][2];
#pragma unroll
  for (int j = 0; j < 2; ++j)
#pragma unroll
    for (int hh = 0; hh < 2; ++hh)
      qf[j][hh] = *(const bf16x8*)&qbase[(size_t)(qw0 + j * 16 + c) * DHEAD + hh * 32 + g * 8];

  f32x4 o[4][2] = {};
  float m[2]  = {-3.0e38f, -3.0e38f};
  float ls[2] = {0.0f, 0.0f};

  const int r8 = l >> 3, ch = l & 7;
  const int sw16 = (ch ^ r8) * 16;

  auto stage = [&](int buf, int kt) {
    const int kb0 = kt * 64;
#pragma unroll
    for (int i = 0; i < 2; ++i) {
      const int row = w * 8 + i * 32 + r8;
      async16((const char*)kbase + (size_t)(kb0 + row) * 128 + sw16,
              (char*)sK[buf] + w * 1024 + i * 4096);
      async16((const char*)vbase + (size_t)row * (SEQ * 2) + (size_t)kb0 * 2 + sw16,
              (char*)sV[buf] + w * 1024 + i * 4096);
    }
  };

  const int nkt = blockIdx.x * 2 + 2;
  stage(0, 0);

  for (int kt = 0; kt < nkt; ++kt) {
    const int cur = kt & 1;
    if (kt + 1 < nkt) {
      stage(cur ^ 1, kt + 1);
      asm volatile("s_waitcnt vmcnt(4)" ::: "memory");
    } else {
      asm volatile("s_waitcnt vmcnt(0)" ::: "memory");
    }
    __builtin_amdgcn_s_barrier();

    const int kb0 = kt * 64;
    if (kb0 < qw0 + 32) {
      const u16* sKc = sK[cur];
      const u16* sVc = sV[cur];
      const int cx = c & 7;

      f32x4 st[4][2];
#pragma unroll
      for (int s = 0; s < 4; ++s) {
        const int row = s * 16 + c;
        bf16x8 kf0 = *(const bf16x8*)&sKc[row * 64 + ((0 + g) ^ cx) * 8];
        bf16x8 kf1 = *(const bf16x8*)&sKc[row * 64 + ((4 + g) ^ cx) * 8];
#pragma unroll
        for (int j = 0; j < 2; ++j) {
          f32x4 z4 = {};
          z4 = __builtin_amdgcn_mfma_f32_16x16x32_bf16(kf0, qf[j][0], z4, 0, 0, 0);
          z4 = __builtin_amdgcn_mfma_f32_16x16x32_bf16(kf1, qf[j][1], z4, 0, 0, 0);
          st[s][j] = z4;
        }
      }

      const bool full = (kb0 + 64 <= qw0 + 1);
      float tmax[2] = {-3.0e38f, -3.0e38f};
#pragma unroll
      for (int s = 0; s < 4; ++s)
#pragma unroll
        for (int j = 0; j < 2; ++j)
#pragma unroll
          for (int i = 0; i < 4; ++i) {
            float vsc = st[s][j][i] * 0.125f;
            if (!full) {
              const int key = kb0 + s * 16 + g * 4 + i;
              vsc = (key <= qw0 + j * 16 + c) ? vsc : -1.0e30f;
            }
            st[s][j][i] = vsc;
            tmax[j] = fmaxf(tmax[j], vsc);
          }
#pragma unroll
      for (int j = 0; j < 2; ++j) {
        tmax[j] = fmaxf(tmax[j], __shfl_xor(tmax[j], 16));
        tmax[j] = fmaxf(tmax[j], __shfl_xor(tmax[j], 32));
      }
      float mnew[2], sc[2], psum[2];
#pragma unroll
      for (int j = 0; j < 2; ++j) {
        mnew[j] = fmaxf(m[j], tmax[j]);
        sc[j]   = __expf(m[j] - mnew[j]);
        psum[j] = 0.0f;
      }
#pragma unroll
      for (int s = 0; s < 4; ++s)
#pragma unroll
        for (int j = 0; j < 2; ++j)
#pragma unroll
          for (int i = 0; i < 4; ++i) {
            const float pv = __expf(st[s][j][i] - mnew[j]);
            st[s][j][i] = pv;
            psum[j] += pv;
          }
#pragma unroll
      for (int j = 0; j < 2; ++j) {
        psum[j] += __shfl_xor(psum[j], 16);
        psum[j] += __shfl_xor(psum[j], 32);
        ls[j] = ls[j] * sc[j] + psum[j];
        m[j]  = mnew[j];
#pragma unroll
        for (int d = 0; d < 4; ++d) o[d][j] = o[d][j] * sc[j];
      }

      u16* pw = pb[w];
#pragma unroll
      for (int s = 0; s < 4; ++s)
#pragma unroll
        for (int j = 0; j < 2; ++j) {
          const int row = j * 16 + c;
          const int swz = (s * 2 + (g >> 1)) ^ cx;
          ushort4 pv4;
          pv4.x = f2bf(st[s][j][0]); pv4.y = f2bf(st[s][j][1]);
          pv4.z = f2bf(st[s][j][2]); pv4.w = f2bf(st[s][j][3]);
          *(ushort4*)&pw[row * 64 + swz * 8 + (g & 1) * 4] = pv4;
        }

      bf16x8 pf[2][2];
#pragma unroll
      for (int j = 0; j < 2; ++j)
#pragma unroll
        for (int ks = 0; ks < 2; ++ks)
          pf[j][ks] = *(const bf16x8*)&pw[(j * 16 + c) * 64 + ((ks * 4 + g) ^ cx) * 8];

#pragma unroll
      for (int d = 0; d < 4; ++d) {
        const int vrow = d * 16 + c;
#pragma unroll
        for (int ks = 0; ks < 2; ++ks) {
          bf16x8 vf = *(const bf16x8*)&sVc[vrow * 64 + ((ks * 4 + g) ^ cx) * 8];
#pragma unroll
          for (int j = 0; j < 2; ++j)
            o[d][j] = __builtin_amdgcn_mfma_f32_16x16x32_bf16(vf, pf[j][ks], o[d][j], 0, 0, 0);
        }
      }
    }
    __builtin_amdgcn_s_barrier();
  }

  const int b = bh >> 4, h = bh & 15;
#pragma unroll
  for (int j = 0; j < 2; ++j) {
    const float inv = 1.0f / ls[j];
    const int qrow = qw0 + j * 16 + c;
    u16* zr = z + ((size_t)b * SEQ + qrow) * D_MODEL + h * DHEAD;
#pragma unroll
    for (int d = 0; d < 4; ++d) {
      ushort4 ov;
      ov.x = f2bf(o[d][j][0] * inv); ov.y = f2bf(o[d][j][1] * inv);
      ov.z = f2bf(o[d][j][2] * inv); ov.w = f2bf(o[d][j][3] * inv);
      *(ushort4*)&zr[d * 16 + g * 4] = ov;
    }
  }
}

// ---------- host ----------
extern "C" void kernel_launch(void* const* d_in, const int* in_sizes, int n_in,
                              void* d_out, int out_size, void* d_ws, size_t ws_size,
                              hipStream_t stream) {
  (void)in_sizes; (void)n_in; (void)out_size; (void)ws_size;
  const float* x   = (const float*)d_in[0];
  const float* g1  = (const float*)d_in[1];
  const float* s1  = (const float*)d_in[2];
  const float* Wq  = (const float*)d_in[3];
  const float* Wk  = (const float*)d_in[4];
  const float* Wv  = (const float*)d_in[5];
  const float* Wo  = (const float*)d_in[6];
  const float* bo  = (const float*)d_in[7];
  const float* g2  = (const float*)d_in[8];
  const float* s2  = (const float*)d_in[9];
  const float* W1  = (const float*)d_in[10];
  const float* b1  = (const float*)d_in[11];
  const float* W2  = (const float*)d_in[12];
  const float* b2  = (const float*)d_in[13];
  float* out = (float*)d_out;
  char* ws = (char*)d_ws;
  const size_t MB = 1024 * 1024;

  u16* wqkvT = (u16*)(ws + 0 * MB);   // 6 MB  [3072,1024] = Wq^T | Wk^T | Wv^T
  u16* woT = (u16*)(ws + 6 * MB);     // 2 MB
  u16* w1T = (u16*)(ws + 8 * MB);     // 8 MB  [4096,1024]
  u16* w2T = (u16*)(ws + 16 * MB);    // 8 MB  [1024,4096]
  u16* x1  = (u16*)(ws + 24 * MB);    // 16 MB
  u16* qb  = (u16*)(ws + 40 * MB);    // 16 MB
  u16* kb  = (u16*)(ws + 56 * MB);    // 16 MB
  u16* vb  = (u16*)(ws + 72 * MB);    // 16 MB
  u16* hb  = (u16*)(ws + 24 * MB);    // 64 MB, aliases x1/q/k/v (dead by MLP1)
  u16* zb  = (u16*)(ws + 88 * MB);    // 16 MB
  u16* y1  = (u16*)(ws + 88 * MB);    // 16 MB, aliases zb (dead after Wo proj)
  float* yb = (float*)(ws + 104 * MB); // 32 MB -> total 136 MB

  // 1. weight convert + transpose
  wconv_kernel<<<dim3(32, 32), 256, 0, stream>>>(Wq, wqkvT, 1024, 1024);
  wconv_kernel<<<dim3(32, 32), 256, 0, stream>>>(Wk, wqkvT + 1024 * 1024, 1024, 1024);
  wconv_kernel<<<dim3(32, 32), 256, 0, stream>>>(Wv, wqkvT + 2048 * 1024, 1024, 1024);
  wconv_kernel<<<dim3(32, 32), 256, 0, stream>>>(Wo, woT, 1024, 1024);
  wconv_kernel<<<dim3(128, 32), 256, 0, stream>>>(W1, w1T, 1024, 4096);
  wconv_kernel<<<dim3(32, 128), 256, 0, stream>>>(W2, w2T, 4096, 1024);
  // 2. LN1
  ln_kernel<<<NROW, 256, 0, stream>>>(x, g1, s1, x1);
  // 3. fused QKV projection (N=3072), head-split scatter epilogue
  gemm8<MODE_QKV, 4><<<64 * 12, 512, 0, stream>>>(x1, wqkvT, nullptr, nullptr,
                                                  qb, kb, vb, 64, 12, 3072, 1024);
  // 4. attention
  attn_kernel<<<dim3(8, 128), 256, 0, stream>>>(qb, kb, vb, zb);
  // 5. output projection + residual (fp32 y)
  gemm8<MODE_F32_RES, 4><<<64 * 4, 512, 0, stream>>>(zb, woT, bo, x,
                                                     yb, nullptr, nullptr, 64, 4, 1024, 1024);
  // 6. LN2
  ln_kernel<<<NROW, 256, 0, stream>>>(yb, g2, s2, y1);
  // 7. MLP up + GELU (256^2 tiles)
  gemm8<MODE_GELU, 8><<<32 * 16, 512, 0, stream>>>(y1, w1T, b1, nullptr,
                                                   hb, nullptr, nullptr, 32, 16, 4096, 1024);
  // 8. MLP down + bias + residual -> out
  gemm8<MODE_F32_RES, 4><<<64 * 4, 512, 0, stream>>>(hb, w2T, b2, yb,
                                                     out, nullptr, nullptr, 64, 4, 1024, 4096);
}

// Round 7
// 401.278 us; speedup vs baseline: 1.1543x; 1.1336x over previous
//
#include <hip/hip_runtime.h>

typedef unsigned short u16;
typedef __bf16 bf16x8 __attribute__((ext_vector_type(8)));
typedef float f32x4 __attribute__((ext_vector_type(4)));

#define D_MODEL 1024
#define NHEAD 16
#define DHEAD 64
#define BATCH 8
#define SEQ 1024
#define NROW 8192   // BATCH*SEQ

// ---------- helpers ----------
__device__ __forceinline__ u16 f2bf(float f) {
  union { float f; unsigned int u; } a; a.f = f;
  unsigned int u = a.u;
  return (u16)((u + 0x7fffu + ((u >> 16) & 1u)) >> 16);
}

// gelu_tanh(x) == x * sigmoid(2*c*(x+0.044715x^3)); single v_exp_f32, NaN-safe.
__device__ __forceinline__ float gelu_f(float x) {
  float y = 0.79788456080286535588f * (x + 0.044715f * x * x * x);
  return x / (1.0f + __expf(-2.0f * y));
}

__device__ __forceinline__ void async16(const void* gsrc, void* ldst) {
  __builtin_amdgcn_global_load_lds((__attribute__((address_space(1))) void*)gsrc,
                                   (__attribute__((address_space(3))) void*)ldst,
                                   16, 0, 0);
}

// ---------- weight fp32 [K,N] -> bf16 W^T [N,K] ----------
__global__ __launch_bounds__(256)
void wconv_kernel(const float* __restrict__ W, u16* __restrict__ WT, int K, int N) {
  __shared__ float tile[32][33];
  const int tx = threadIdx.x & 31, ty = threadIdx.x >> 5;
  const int n0 = blockIdx.x * 32, k0 = blockIdx.y * 32;
#pragma unroll
  for (int r = 0; r < 4; ++r)
    tile[ty + r * 8][tx] = W[(size_t)(k0 + ty + r * 8) * N + n0 + tx];
  __syncthreads();
#pragma unroll
  for (int r = 0; r < 4; ++r)
    WT[(size_t)(n0 + ty + r * 8) * K + k0 + tx] = f2bf(tile[tx][ty + r * 8]);
}

// ---------- layernorm fp32 -> bf16 ----------
__global__ __launch_bounds__(256)
void ln_kernel(const float* __restrict__ x, const float* __restrict__ gamma,
               const float* __restrict__ beta, u16* __restrict__ out) {
  const int row = blockIdx.x, t = threadIdx.x;
  const float4 v = ((const float4*)(x + (size_t)row * D_MODEL))[t];
  float s  = v.x + v.y + v.z + v.w;
  float s2 = v.x * v.x + v.y * v.y + v.z * v.z + v.w * v.w;
#pragma unroll
  for (int off = 32; off >= 1; off >>= 1) {
    s  += __shfl_down(s, off);
    s2 += __shfl_down(s2, off);
  }
  __shared__ float red[8];
  const int w = t >> 6, l = t & 63;
  if (l == 0) { red[w] = s; red[4 + w] = s2; }
  __syncthreads();
  s  = red[0] + red[1] + red[2] + red[3];
  s2 = red[4] + red[5] + red[6] + red[7];
  const float mean = s * (1.0f / D_MODEL);
  const float var  = s2 * (1.0f / D_MODEL) - mean * mean;
  const float inv  = rsqrtf(var + 1e-5f);
  const float4 ga = ((const float4*)gamma)[t];
  const float4 be = ((const float4*)beta)[t];
  ushort4 ov;
  ov.x = f2bf((v.x - mean) * inv * ga.x + be.x);
  ov.y = f2bf((v.y - mean) * inv * ga.y + be.y);
  ov.z = f2bf((v.z - mean) * inv * ga.z + be.z);
  ov.w = f2bf((v.w - mean) * inv * ga.w + be.w);
  ((ushort4*)out)[(size_t)row * 256 + t] = ov;
}

// ---------- GEMM: C[M,N] = A[M,K](bf16) * B (given as B^T [N,K] bf16) ----------
// 2-phase double-buffered (proven round-3 structure): stage(next) issued BEFORE
// ds_read+MFMA of current; one vmcnt(0)+barrier per K-step.
#define MODE_QKV 0
#define MODE_F32_RES 2
#define MODE_GELU 3

template <int MODE>
__global__ __launch_bounds__(256, 4)
void gemm_bt(const u16* __restrict__ A, const u16* __restrict__ BT,
             const float* __restrict__ bias, const float* __restrict__ resid,
             void* __restrict__ outp, u16* __restrict__ out2, u16* __restrict__ out3,
             int M, int N, int K) {
  __shared__ u16 sA[2][128 * 32];
  __shared__ u16 sB[2][128 * 32];
  const int t = threadIdx.x;
  const int w = t >> 6, l = t & 63;
  const int c = l & 15, g = l >> 4;
  const int wr = w >> 1, wc = w & 1;
  const int bm = blockIdx.x, bn = blockIdx.y;

  f32x4 acc[4][4] = {};

  const char* Ab = (const char*)(A + (size_t)bm * 128 * K);
  const char* Bb = (const char*)(BT + (size_t)bn * 128 * K);
  const size_t ldb = (size_t)K * 2;
  const int srow = t >> 2;            // 4 threads x 16B cover one 64B row
  const int scolb = (t & 3) * 16;
  const int ldsoff = w * 1024;

  auto stage = [&](int buf, int k0) {
#pragma unroll
    for (int i = 0; i < 2; ++i) {
      async16(Ab + (size_t)(srow + i * 64) * ldb + (size_t)k0 * 2 + scolb,
              (char*)sA[buf] + i * 4096 + ldsoff);
      async16(Bb + (size_t)(srow + i * 64) * ldb + (size_t)k0 * 2 + scolb,
              (char*)sB[buf] + i * 4096 + ldsoff);
    }
  };

  stage(0, 0);
  asm volatile("s_waitcnt vmcnt(0)" ::: "memory");
  __builtin_amdgcn_s_barrier();

  const int nt = K >> 5;
  for (int it = 0; it < nt; ++it) {
    const int cur = it & 1;
    if (it + 1 < nt) stage(cur ^ 1, (it + 1) << 5);   // prefetch overlaps compute
    bf16x8 af[4], bfr[4];
#pragma unroll
    for (int m = 0; m < 4; ++m)
      af[m] = *(const bf16x8*)&sA[cur][(wr * 64 + m * 16 + c) * 32 + g * 8];
#pragma unroll
    for (int n = 0; n < 4; ++n)
      bfr[n] = *(const bf16x8*)&sB[cur][(wc * 64 + n * 16 + c) * 32 + g * 8];
#pragma unroll
    for (int m = 0; m < 4; ++m)
#pragma unroll
      for (int n = 0; n < 4; ++n)
        acc[m][n] = __builtin_amdgcn_mfma_f32_16x16x32_bf16(af[m], bfr[n], acc[m][n], 0, 0, 0);
    asm volatile("s_waitcnt vmcnt(0)" ::: "memory");  // prefetched tile resident
    __builtin_amdgcn_s_barrier();                      // all waves' reads of cur done
  }

#pragma unroll
  for (int m = 0; m < 4; ++m) {
    const int r0 = bm * 128 + wr * 64 + m * 16 + g * 4;
#pragma unroll
    for (int n = 0; n < 4; ++n) {
      const int cc = bn * 128 + wc * 64 + n * 16 + c;
#pragma unroll
      for (int i = 0; i < 4; ++i) {
        const int r = r0 + i;
        const float v = acc[m][n][i];
        if constexpr (MODE == MODE_QKV) {
          // fused QKV: cc in [0,3072): sel 0->q [b,h,t,dh], 1->k [b,h,t,dh], 2->v [b,h,dh,t]
          const int sel = cc >> 10, ccl = cc & 1023;
          const int bb = r >> 10, tt = r & 1023, h = ccl >> 6, dh = ccl & 63;
          if (sel == 0)
            ((u16*)outp)[(((size_t)bb * NHEAD + h) * SEQ + tt) * DHEAD + dh] = f2bf(v);
          else if (sel == 1)
            out2[(((size_t)bb * NHEAD + h) * SEQ + tt) * DHEAD + dh] = f2bf(v);
          else
            out3[(((size_t)bb * NHEAD + h) * DHEAD + dh) * SEQ + tt] = f2bf(v);
        } else if constexpr (MODE == MODE_F32_RES) {
          const size_t idx = (size_t)r * N + cc;
          ((float*)outp)[idx] = v + bias[cc] + resid[idx];
        } else {
          const size_t idx = (size_t)r * N + cc;
          ((u16*)outp)[idx] = f2bf(gelu_f(v + bias[cc]));
        }
      }
    }
  }
}

// ---------- causal flash attention ----------
// 4 waves/block, QBLK=32 rows/wave, KVBLK=64, K/V LDS double-buffered
// via global_load_lds with XOR chunk swizzle; counted vmcnt + raw barriers.
__global__ __launch_bounds__(256, 3)
void attn_kernel(const u16* __restrict__ q, const u16* __restrict__ k,
                 const u16* __restrict__ vT, u16* __restrict__ z) {
  __shared__ u16 sK[2][64 * 64];
  __shared__ u16 sV[2][64 * 64];
  __shared__ u16 pb[4][32 * 64];

  const int t = threadIdx.x, w = t >> 6, l = t & 63;
  const int c = l & 15, g = l >> 4;
  const int bh = blockIdx.y;
  const int qb0 = blockIdx.x * 128;
  const int qw0 = qb0 + w * 32;

  const u16* qbase = q  + (size_t)bh * SEQ * DHEAD;
  const u16* kbase = k  + (size_t)bh * SEQ * DHEAD;
  const u16* vbase = vT + (size_t)bh * DHEAD * SEQ;

  bf16x8 qf[2][2];
#pragma unroll
  for (int j = 0; j < 2; ++j)
#pragma unroll
    for (int hh = 0; hh < 2; ++hh)
      qf[j][hh] = *(const bf16x8*)&qbase[(size_t)(qw0 + j * 16 + c) * DHEAD + hh * 32 + g * 8];

  f32x4 o[4][2] = {};
  float m[2]  = {-3.0e38f, -3.0e38f};
  float ls[2] = {0.0f, 0.0f};

  const int r8 = l >> 3, ch = l & 7;
  const int sw16 = (ch ^ r8) * 16;

  auto stage = [&](int buf, int kt) {
    const int kb0 = kt * 64;
#pragma unroll
    for (int i = 0; i < 2; ++i) {
      const int row = w * 8 + i * 32 + r8;
      async16((const char*)kbase + (size_t)(kb0 + row) * 128 + sw16,
              (char*)sK[buf] + w * 1024 + i * 4096);
      async16((const char*)vbase + (size_t)row * (SEQ * 2) + (size_t)kb0 * 2 + sw16,
              (char*)sV[buf] + w * 1024 + i * 4096);
    }
  };

  const int nkt = blockIdx.x * 2 + 2;
  stage(0, 0);

  for (int kt = 0; kt < nkt; ++kt) {
    const int cur = kt & 1;
    if (kt + 1 < nkt) {
      stage(cur ^ 1, kt + 1);
      asm volatile("s_waitcnt vmcnt(4)" ::: "memory");
    } else {
      asm volatile("s_waitcnt vmcnt(0)" ::: "memory");
    }
    __builtin_amdgcn_s_barrier();

    const int kb0 = kt * 64;
    if (kb0 < qw0 + 32) {
      const u16* sKc = sK[cur];
      const u16* sVc = sV[cur];
      const int cx = c & 7;

      f32x4 st[4][2];
#pragma unroll
      for (int s = 0; s < 4; ++s) {
        const int row = s * 16 + c;
        bf16x8 kf0 = *(const bf16x8*)&sKc[row * 64 + ((0 + g) ^ cx) * 8];
        bf16x8 kf1 = *(const bf16x8*)&sKc[row * 64 + ((4 + g) ^ cx) * 8];
#pragma unroll
        for (int j = 0; j < 2; ++j) {
          f32x4 z4 = {};
          z4 = __builtin_amdgcn_mfma_f32_16x16x32_bf16(kf0, qf[j][0], z4, 0, 0, 0);
          z4 = __builtin_amdgcn_mfma_f32_16x16x32_bf16(kf1, qf[j][1], z4, 0, 0, 0);
          st[s][j] = z4;
        }
      }

      const bool full = (kb0 + 64 <= qw0 + 1);
      float tmax[2] = {-3.0e38f, -3.0e38f};
#pragma unroll
      for (int s = 0; s < 4; ++s)
#pragma unroll
        for (int j = 0; j < 2; ++j)
#pragma unroll
          for (int i = 0; i < 4; ++i) {
            float vsc = st[s][j][i] * 0.125f;
            if (!full) {
              const int key = kb0 + s * 16 + g * 4 + i;
              vsc = (key <= qw0 + j * 16 + c) ? vsc : -1.0e30f;
            }
            st[s][j][i] = vsc;
            tmax[j] = fmaxf(tmax[j], vsc);
          }
#pragma unroll
      for (int j = 0; j < 2; ++j) {
        tmax[j] = fmaxf(tmax[j], __shfl_xor(tmax[j], 16));
        tmax[j] = fmaxf(tmax[j], __shfl_xor(tmax[j], 32));
      }
      float mnew[2], sc[2], psum[2];
#pragma unroll
      for (int j = 0; j < 2; ++j) {
        mnew[j] = fmaxf(m[j], tmax[j]);
        sc[j]   = __expf(m[j] - mnew[j]);
        psum[j] = 0.0f;
      }
#pragma unroll
      for (int s = 0; s < 4; ++s)
#pragma unroll
        for (int j = 0; j < 2; ++j)
#pragma unroll
          for (int i = 0; i < 4; ++i) {
            const float pv = __expf(st[s][j][i] - mnew[j]);
            st[s][j][i] = pv;
            psum[j] += pv;
          }
#pragma unroll
      for (int j = 0; j < 2; ++j) {
        psum[j] += __shfl_xor(psum[j], 16);
        psum[j] += __shfl_xor(psum[j], 32);
        ls[j] = ls[j] * sc[j] + psum[j];
        m[j]  = mnew[j];
#pragma unroll
        for (int d = 0; d < 4; ++d) o[d][j] = o[d][j] * sc[j];
      }

      u16* pw = pb[w];
#pragma unroll
      for (int s = 0; s < 4; ++s)
#pragma unroll
        for (int j = 0; j < 2; ++j) {
          const int row = j * 16 + c;
          const int swz = (s * 2 + (g >> 1)) ^ cx;
          ushort4 pv4;
          pv4.x = f2bf(st[s][j][0]); pv4.y = f2bf(st[s][j][1]);
          pv4.z = f2bf(st[s][j][2]); pv4.w = f2bf(st[s][j][3]);
          *(ushort4*)&pw[row * 64 + swz * 8 + (g & 1) * 4] = pv4;
        }

      bf16x8 pf[2][2];
#pragma unroll
      for (int j = 0; j < 2; ++j)
#pragma unroll
        for (int ks = 0; ks < 2; ++ks)
          pf[j][ks] = *(const bf16x8*)&pw[(j * 16 + c) * 64 + ((ks * 4 + g) ^ cx) * 8];

#pragma unroll
      for (int d = 0; d < 4; ++d) {
        const int vrow = d * 16 + c;
#pragma unroll
        for (int ks = 0; ks < 2; ++ks) {
          bf16x8 vf = *(const bf16x8*)&sVc[vrow * 64 + ((ks * 4 + g) ^ cx) * 8];
#pragma unroll
          for (int j = 0; j < 2; ++j)
            o[d][j] = __builtin_amdgcn_mfma_f32_16x16x32_bf16(vf, pf[j][ks], o[d][j], 0, 0, 0);
        }
      }
    }
    __builtin_amdgcn_s_barrier();
  }

  const int b = bh >> 4, h = bh & 15;
#pragma unroll
  for (int j = 0; j < 2; ++j) {
    const float inv = 1.0f / ls[j];
    const int qrow = qw0 + j * 16 + c;
    u16* zr = z + ((size_t)b * SEQ + qrow) * D_MODEL + h * DHEAD;
#pragma unroll
    for (int d = 0; d < 4; ++d) {
      ushort4 ov;
      ov.x = f2bf(o[d][j][0] * inv); ov.y = f2bf(o[d][j][1] * inv);
      ov.z = f2bf(o[d][j][2] * inv); ov.w = f2bf(o[d][j][3] * inv);
      *(ushort4*)&zr[d * 16 + g * 4] = ov;
    }
  }
}

// ---------- host ----------
extern "C" void kernel_launch(void* const* d_in, const int* in_sizes, int n_in,
                              void* d_out, int out_size, void* d_ws, size_t ws_size,
                              hipStream_t stream) {
  (void)in_sizes; (void)n_in; (void)out_size; (void)ws_size;
  const float* x   = (const float*)d_in[0];
  const float* g1  = (const float*)d_in[1];
  const float* s1  = (const float*)d_in[2];
  const float* Wq  = (const float*)d_in[3];
  const float* Wk  = (const float*)d_in[4];
  const float* Wv  = (const float*)d_in[5];
  const float* Wo  = (const float*)d_in[6];
  const float* bo  = (const float*)d_in[7];
  const float* g2  = (const float*)d_in[8];
  const float* s2  = (const float*)d_in[9];
  const float* W1  = (const float*)d_in[10];
  const float* b1  = (const float*)d_in[11];
  const float* W2  = (const float*)d_in[12];
  const float* b2  = (const float*)d_in[13];
  float* out = (float*)d_out;
  char* ws = (char*)d_ws;
  const size_t MB = 1024 * 1024;

  u16* wqkvT = (u16*)(ws + 0 * MB);   // 6 MB  [3072,1024] = Wq^T | Wk^T | Wv^T
  u16* woT = (u16*)(ws + 6 * MB);     // 2 MB
  u16* w1T = (u16*)(ws + 8 * MB);     // 8 MB  [4096,1024]
  u16* w2T = (u16*)(ws + 16 * MB);    // 8 MB  [1024,4096]
  u16* x1  = (u16*)(ws + 24 * MB);    // 16 MB
  u16* qb  = (u16*)(ws + 40 * MB);    // 16 MB
  u16* kb  = (u16*)(ws + 56 * MB);    // 16 MB
  u16* vb  = (u16*)(ws + 72 * MB);    // 16 MB
  u16* hb  = (u16*)(ws + 24 * MB);    // 64 MB, aliases x1/q/k/v (dead by MLP1)
  u16* zb  = (u16*)(ws + 88 * MB);    // 16 MB
  u16* y1  = (u16*)(ws + 88 * MB);    // 16 MB, aliases zb (dead after Wo proj)
  float* yb = (float*)(ws + 104 * MB); // 32 MB -> total 136 MB

  // 1. weight convert + transpose
  wconv_kernel<<<dim3(32, 32), 256, 0, stream>>>(Wq, wqkvT, 1024, 1024);
  wconv_kernel<<<dim3(32, 32), 256, 0, stream>>>(Wk, wqkvT + 1024 * 1024, 1024, 1024);
  wconv_kernel<<<dim3(32, 32), 256, 0, stream>>>(Wv, wqkvT + 2048 * 1024, 1024, 1024);
  wconv_kernel<<<dim3(32, 32), 256, 0, stream>>>(Wo, woT, 1024, 1024);
  wconv_kernel<<<dim3(128, 32), 256, 0, stream>>>(W1, w1T, 1024, 4096);
  wconv_kernel<<<dim3(32, 128), 256, 0, stream>>>(W2, w2T, 4096, 1024);
  // 2. LN1
  ln_kernel<<<NROW, 256, 0, stream>>>(x, g1, s1, x1);
  // 3. fused QKV projection (N=3072), head-split scatter epilogue
  gemm_bt<MODE_QKV><<<dim3(64, 24), 256, 0, stream>>>(x1, wqkvT, nullptr, nullptr,
                                                      qb, kb, vb, NROW, 3072, 1024);
  // 4. attention
  attn_kernel<<<dim3(8, 128), 256, 0, stream>>>(qb, kb, vb, zb);
  // 5. output projection + residual (fp32 y)
  gemm_bt<MODE_F32_RES><<<dim3(64, 8), 256, 0, stream>>>(zb, woT, bo, x,
                                                         yb, nullptr, nullptr, NROW, 1024, 1024);
  // 6. LN2
  ln_kernel<<<NROW, 256, 0, stream>>>(yb, g2, s2, y1);
  // 7. MLP up + GELU
  gemm_bt<MODE_GELU><<<dim3(64, 32), 256, 0, stream>>>(y1, w1T, b1, nullptr,
                                                       hb, nullptr, nullptr, NROW, 4096, 1024);
  // 8. MLP down + bias + residual -> out
  gemm_bt<MODE_F32_RES><<<dim3(64, 8), 256, 0, stream>>>(hb, w2T, b2, yb,
                                                         out, nullptr, nullptr, NROW, 1024, 4096);
}